// Round 5
// baseline (93.502 us; speedup 1.0000x reference)
//
#include <hip/hip_runtime.h>

#define Bn 2
#define Nn 4096
#define Cn 256
#define Kn 64
#define BK (Bn * Kn)
#define NT 1024              // 16 waves per block
#define NW 16

static __device__ __forceinline__ float4 fmax4(float4 a, float4 b) {
    return make_float4(fmaxf(a.x, b.x), fmaxf(a.y, b.y),
                       fmaxf(a.z, b.z), fmaxf(a.w, b.w));
}

// One block per (b,k), 1024 threads.
// Pooling: wave w covers a full 256-ch row via float4/lane; 16 rows in flight.
__global__ __launch_bounds__(NT) void roi_onepass_v2(
    const float* __restrict__ points,      // (B,N,3)
    const float* __restrict__ feats,       // (B,N,C)
    const float* __restrict__ proposals,   // (B,K,7)
    const float* __restrict__ W1,          // (C,256)
    const float* __restrict__ b1,
    const float* __restrict__ W2,          // (256,256)
    const float* __restrict__ b2,
    float* __restrict__ out)               // (B,K,256)
{
    const int bk   = blockIdx.x;
    const int b    = bk / Kn;
    const int tid  = threadIdx.x;
    const int w    = tid >> 6;             // wave 0..15
    const int l    = tid & 63;             // lane in wave

    __shared__ int s_idx[Nn];              // 16 KiB
    __shared__ int s_count;
    __shared__ __align__(16) float s_red[NW][Cn];   // 16 KiB
    __shared__ float s_vec[Cn];

    // --- box bounds (strict inequalities; ry ignored — matches reference) ---
    const float* prop = proposals + (size_t)bk * 7;
    const float cx = prop[0], cy = prop[1], cz = prop[2];
    const float hx = prop[3] * 0.5f, hy = prop[4] * 0.5f, hz = prop[5] * 0.5f;
    const float lox = cx - hx, loy = cy - hy, loz = cz - hz;
    const float hix = cx + hx, hiy = cy + hy, hiz = cz + hz;

    if (tid == 0) s_count = 0;
    __syncthreads();

    // --- mask + ballot compaction (1 shared atomic per wave-iter) ---
    const float* pts = points + (size_t)b * Nn * 3;
    #pragma unroll
    for (int n = tid; n < Nn; n += NT) {
        const float px = pts[n * 3 + 0];
        const float py = pts[n * 3 + 1];
        const float pz = pts[n * 3 + 2];
        const bool in = (px > lox) & (px < hix) &
                        (py > loy) & (py < hiy) &
                        (pz > loz) & (pz < hiz);
        const unsigned long long mask = __ballot(in);
        int base = 0;
        if (l == 0) base = atomicAdd(&s_count, __popcll(mask));
        base = __shfl(base, 0);
        if (in) s_idx[base + __popcll(mask & ((1ull << l) - 1ull))] = n;
    }
    __syncthreads();
    const int count = s_count;

    // --- pooling: wave w handles cpw rows; 16 rows in flight per batch ---
    float4 m4 = make_float4(-INFINITY, -INFINITY, -INFINITY, -INFINITY);
    if (count > 0) {
        const int cpw = (count + NW - 1) >> 4;         // rows per wave
        const int i0  = w * cpw;
        const float4* fb4 = (const float4*)(feats + (size_t)b * Nn * Cn);
        for (int i = i0; i < i0 + cpw; i += 16) {
            float4 v[16];
            #pragma unroll
            for (int t = 0; t < 16; ++t) {
                int j = i + t;
                j = (j < count) ? j : (count - 1);     // max is idempotent
                const int n = s_idx[j];
                v[t] = fb4[(size_t)n * 64 + l];
            }
            // tree reduce
            #pragma unroll
            for (int t = 0; t < 8; ++t) v[t] = fmax4(v[t], v[t + 8]);
            #pragma unroll
            for (int t = 0; t < 4; ++t) v[t] = fmax4(v[t], v[t + 4]);
            v[0] = fmax4(fmax4(v[0], v[1]), fmax4(v[2], v[3]));
            m4 = fmax4(m4, v[0]);
        }
    }
    ((float4*)&s_red[w][0])[l] = m4;
    __syncthreads();

    // --- cross-wave max reduce: 16 -> 4 -> 1 ---
    {
        const int c = tid & 255, g = tid >> 8;
        const float a = fmaxf(fmaxf(s_red[4 * g + 0][c], s_red[4 * g + 1][c]),
                              fmaxf(s_red[4 * g + 2][c], s_red[4 * g + 3][c]));
        s_red[4 * g][c] = a;      // cells [4g..4g+3][c] touched only by this thread
    }
    __syncthreads();
    if (tid < 256) {
        float mm = fmaxf(fmaxf(s_red[0][tid], s_red[4][tid]),
                         fmaxf(s_red[8][tid], s_red[12][tid]));
        if (count == 0) mm = 0.0f;             // empty box -> 0
        s_vec[tid] = mm;
    }
    __syncthreads();

    // --- MLP: K split 4-ways across thread groups ---
    const int grp = tid >> 8, lane = tid & 255;
    {
        const int c0 = grp * 64;
        float acc = 0.0f;
        #pragma unroll 16
        for (int j = 0; j < 64; ++j) {
            const int c = c0 + j;
            acc = fmaf(s_vec[c], W1[c * Cn + lane], acc);
        }
        s_red[grp][lane] = acc;
    }
    __syncthreads();
    const float h = fmaxf(s_red[0][lane] + s_red[1][lane] +
                          s_red[2][lane] + s_red[3][lane] + b1[lane], 0.0f);
    __syncthreads();
    if (grp == 0) s_vec[lane] = h;
    __syncthreads();
    {
        const int c0 = grp * 64;
        float acc = 0.0f;
        #pragma unroll 16
        for (int j = 0; j < 64; ++j) {
            const int c = c0 + j;
            acc = fmaf(s_vec[c], W2[c * Cn + lane], acc);
        }
        s_red[grp][lane] = acc;
    }
    __syncthreads();
    if (grp == 0) {
        const float o = fmaxf(s_red[0][lane] + s_red[1][lane] +
                              s_red[2][lane] + s_red[3][lane] + b2[lane], 0.0f);
        out[(size_t)bk * Cn + lane] = o;
    }
}

extern "C" void kernel_launch(void* const* d_in, const int* in_sizes, int n_in,
                              void* d_out, int out_size, void* d_ws, size_t ws_size,
                              hipStream_t stream) {
    const float* points    = (const float*)d_in[0];
    const float* feats     = (const float*)d_in[1];
    const float* proposals = (const float*)d_in[2];
    const float* W1        = (const float*)d_in[3];
    const float* b1        = (const float*)d_in[4];
    const float* W2        = (const float*)d_in[5];
    const float* b2        = (const float*)d_in[6];
    float* out             = (float*)d_out;

    roi_onepass_v2<<<BK, NT, 0, stream>>>(points, feats, proposals,
                                          W1, b1, W2, b2, out);
}